// Round 3
// baseline (1192.174 us; speedup 1.0000x reference)
//
#include <hip/hip_runtime.h>

typedef short bf16x8 __attribute__((ext_vector_type(8)));
typedef float f32x4 __attribute__((ext_vector_type(4)));

#define SEQ 512
#define HID 4096
#define TKV 8192
#define SCALE 0.08838834764831845f  // 1/sqrt(128)

__device__ __forceinline__ ushort f2b(float f) {
  union { float f; unsigned u; } v; v.f = f;
  unsigned u = v.u;
  unsigned r = (u + 0x7FFFu + ((u >> 16) & 1u)) >> 16;  // RNE
  return (ushort)r;
}

// ---------- hidden fp32 -> bf16 ----------
__global__ __launch_bounds__(256) void cvt_hidden(const float* __restrict__ in, ushort* __restrict__ out) {
  int i = (blockIdx.x * 256 + threadIdx.x) * 4;
  float4 v = *(const float4*)(in + i);
  ushort4 o; o.x = f2b(v.x); o.y = f2b(v.y); o.z = f2b(v.z); o.w = f2b(v.w);
  *(ushort4*)(out + i) = o;
}

// ---------- W [K][N] fp32 -> WT [N][K] bf16 ----------
__global__ __launch_bounds__(256) void transpose_cvt(const float* __restrict__ W, ushort* __restrict__ WT) {
  __shared__ float tile[32][33];
  int bx = blockIdx.x, by = blockIdx.y;
  int x = threadIdx.x & 31, y0 = threadIdx.x >> 5;
#pragma unroll
  for (int yy = 0; yy < 32; yy += 8)
    tile[y0 + yy][x] = W[(by * 32 + y0 + yy) * HID + bx * 32 + x];
  __syncthreads();
#pragma unroll
  for (int yy = 0; yy < 32; yy += 8)
    WT[(bx * 32 + y0 + yy) * HID + by * 32 + x] = f2b(tile[x][y0 + yy]);
}

// ---------- paged KV gather: cache[1024][2][8][16][128] fp32 -> Kb/Vb [8][8192][128] bf16 ----------
__global__ __launch_bounds__(256) void gather_kv(const float* __restrict__ cache, const int* __restrict__ btab,
                                                 ushort* __restrict__ Kb, ushort* __restrict__ Vb) {
  int i = blockIdx.x * 256 + threadIdx.x;  // 4,194,304 threads, 4 elems each
  int d4  = i & 31;
  int pos = (i >> 5) & 15;
  int kvh = (i >> 9) & 7;
  int c   = (i >> 12) & 1;
  int blk = i >> 13;
  int b = btab[blk];
  const float4 v = *(const float4*)(cache + (((long)(b * 2 + c) * 8 + kvh) * 16 + pos) * 128 + d4 * 4);
  ushort4 o; o.x = f2b(v.x); o.y = f2b(v.y); o.z = f2b(v.z); o.w = f2b(v.w);
  ushort* dst = (c ? Vb : Kb) + ((long)kvh * TKV + blk * 16 + pos) * 128 + d4 * 4;
  *(ushort4*)dst = o;
}

// ---------- RoPE tables (fp64 for accuracy) ----------
__global__ __launch_bounds__(256) void rope_table(float* __restrict__ ct, float* __restrict__ st) {
  int i = blockIdx.x * 256 + threadIdx.x;  // 512*64
  int s = i >> 6, j = i & 63;
  double invf = exp(-((double)(2 * j) / 128.0) * log(10000.0));
  double ang = (double)s * invf;
  ct[i] = (float)cos(ang);
  st[i] = (float)sin(ang);
}

// ---------- RoPE apply: Qt[s][h*128+d] fp32 -> Qb[h][s][d] bf16 ----------
__global__ __launch_bounds__(256) void rope_apply(const float* __restrict__ Qt, const float* __restrict__ ct,
                                                  const float* __restrict__ st, ushort* __restrict__ Qb) {
  int i = blockIdx.x * 256 + threadIdx.x;  // 2M
  int s = i >> 12;
  int hd = i & 4095;
  int h = hd >> 7, d = hd & 127;
  int j = d & 63;
  float c = ct[s * 64 + j], sn = st[s * 64 + j];
  float q = Qt[i];
  float qp = Qt[(d < 64) ? (i + 64) : (i - 64)];
  float rot = (d < 64) ? -qp : qp;
  Qb[((long)h * SEQ + s) * 128 + d] = f2b(q * c + rot * sn);
}

// ---------- C[M][N] fp32 = A[M][K]bf16 * BT[N][K]bf16^T ; BM=64 BN=128 BK=64, 4 waves ----------
__global__ __launch_bounds__(256) void gemm_bt(const ushort* __restrict__ A, const ushort* __restrict__ BT,
                                               float* __restrict__ C, int M, int N, int K) {
  __shared__ ushort As[64][72];
  __shared__ ushort Bs[128][72];
  int bm = blockIdx.x, bn = blockIdx.y;
  int tid = threadIdx.x, lane = tid & 63, wave = tid >> 6;
  int wm = wave >> 1, wn = wave & 1;
  int l15 = lane & 15, lg = lane >> 4;
  f32x4 acc[2][4] = {};
  for (int kt = 0; kt < K; kt += 64) {
    __syncthreads();
#pragma unroll
    for (int c = 0; c < 2; c++) {
      int idx = tid + c * 256;
      int r = idx >> 3, ch = idx & 7;
      *(uint4*)&As[r][ch * 8] = *(const uint4*)(A + (long)(bm * 64 + r) * K + kt + ch * 8);
    }
#pragma unroll
    for (int c = 0; c < 4; c++) {
      int idx = tid + c * 256;
      int r = idx >> 3, ch = idx & 7;
      *(uint4*)&Bs[r][ch * 8] = *(const uint4*)(BT + (long)(bn * 128 + r) * K + kt + ch * 8);
    }
    __syncthreads();
#pragma unroll
    for (int kk = 0; kk < 2; kk++) {
      bf16x8 af[2], bfr[4];
#pragma unroll
      for (int m = 0; m < 2; m++) af[m] = *(const bf16x8*)(&As[wm * 32 + m * 16 + l15][kk * 32 + lg * 8]);
#pragma unroll
      for (int n = 0; n < 4; n++) bfr[n] = *(const bf16x8*)(&Bs[wn * 64 + n * 16 + l15][kk * 32 + lg * 8]);
#pragma unroll
      for (int m = 0; m < 2; m++)
#pragma unroll
        for (int n = 0; n < 4; n++)
          acc[m][n] = __builtin_amdgcn_mfma_f32_16x16x32_bf16(af[m], bfr[n], acc[m][n], 0, 0, 0);
    }
  }
#pragma unroll
  for (int m = 0; m < 2; m++)
#pragma unroll
    for (int n = 0; n < 4; n++)
#pragma unroll
      for (int r = 0; r < 4; r++) {
        int row = bm * 64 + wm * 32 + m * 16 + lg * 4 + r;
        int col = bn * 128 + wn * 64 + n * 16 + l15;
        C[(long)row * N + col] = acc[m][n][r];
      }
}

// ---------- flash attention: Q[32][512][128], K/V[8][8192][128] -> ctx[512][4096] bf16 ----------
__global__ __launch_bounds__(256) void attn(const ushort* __restrict__ Q, const ushort* __restrict__ Kc,
                                            const ushort* __restrict__ Vc, ushort* __restrict__ ctx) {
  __shared__ ushort Ks[64][136];
  __shared__ ushort Vts[128][72];
  __shared__ ushort Ps[4][16][72];
  int h = blockIdx.x, qb = blockIdx.y;
  int kvh = h >> 2;
  int tid = threadIdx.x, lane = tid & 63, wave = tid >> 6;
  int l15 = lane & 15, lg = lane >> 4;
  bf16x8 qf[4];
  const ushort* qrow = Q + ((long)h * SEQ + qb * 64 + wave * 16 + l15) * 128 + lg * 8;
#pragma unroll
  for (int kk = 0; kk < 4; kk++) qf[kk] = *(const bf16x8*)(qrow + kk * 32);
  f32x4 o[8] = {};
  float mrow[4] = {-3e38f, -3e38f, -3e38f, -3e38f};
  float srow[4] = {0.f, 0.f, 0.f, 0.f};
  const ushort* Kb = Kc + (long)kvh * TKV * 128;
  const ushort* Vb = Vc + (long)kvh * TKV * 128;
  for (int t0 = 0; t0 < TKV; t0 += 64) {
    __syncthreads();
#pragma unroll
    for (int c = 0; c < 4; c++) {
      int idx = tid + c * 256;
      int r = idx >> 4, ch = idx & 15;
      *(uint4*)&Ks[r][ch * 8] = *(const uint4*)(Kb + (long)(t0 + r) * 128 + ch * 8);
      uint4 vv = *(const uint4*)(Vb + (long)(t0 + r) * 128 + ch * 8);
      const ushort* pvv = (const ushort*)&vv;
#pragma unroll
      for (int j = 0; j < 8; j++) Vts[ch * 8 + j][r] = pvv[j];
    }
    __syncthreads();
    f32x4 s[4] = {};
#pragma unroll
    for (int kk = 0; kk < 4; kk++)
#pragma unroll
      for (int n = 0; n < 4; n++) {
        bf16x8 kf = *(const bf16x8*)(&Ks[n * 16 + l15][kk * 32 + lg * 8]);
        s[n] = __builtin_amdgcn_mfma_f32_16x16x32_bf16(qf[kk], kf, s[n], 0, 0, 0);
      }
    float pv4[4][4];
#pragma unroll
    for (int r = 0; r < 4; r++) {
      float a = fmaxf(fmaxf(s[0][r], s[1][r]), fmaxf(s[2][r], s[3][r])) * SCALE;
#pragma unroll
      for (int msk = 1; msk < 16; msk <<= 1) a = fmaxf(a, __shfl_xor(a, msk, 64));
      float mn = fmaxf(mrow[r], a);
      float alpha = __expf(mrow[r] - mn);
      mrow[r] = mn;
      float rs = 0.f;
#pragma unroll
      for (int n = 0; n < 4; n++) { float p = __expf(s[n][r] * SCALE - mn); pv4[n][r] = p; rs += p; }
#pragma unroll
      for (int msk = 1; msk < 16; msk <<= 1) rs += __shfl_xor(rs, msk, 64);
      srow[r] = srow[r] * alpha + rs;
#pragma unroll
      for (int n8 = 0; n8 < 8; n8++) o[n8][r] *= alpha;
    }
#pragma unroll
    for (int n = 0; n < 4; n++)
#pragma unroll
      for (int r = 0; r < 4; r++)
        Ps[wave][lg * 4 + r][n * 16 + l15] = f2b(pv4[n][r]);
    asm volatile("s_waitcnt lgkmcnt(0)" ::: "memory");
#pragma unroll
    for (int kk = 0; kk < 2; kk++) {
      bf16x8 pf = *(const bf16x8*)(&Ps[wave][l15][kk * 32 + lg * 8]);
#pragma unroll
      for (int n8 = 0; n8 < 8; n8++) {
        bf16x8 vf = *(const bf16x8*)(&Vts[n8 * 16 + l15][kk * 32 + lg * 8]);
        o[n8] = __builtin_amdgcn_mfma_f32_16x16x32_bf16(pf, vf, o[n8], 0, 0, 0);
      }
    }
  }
#pragma unroll
  for (int n8 = 0; n8 < 8; n8++)
#pragma unroll
    for (int r = 0; r < 4; r++) {
      int row = qb * 64 + wave * 16 + lg * 4 + r;
      int col = h * 128 + n8 * 16 + l15;
      ctx[(long)row * HID + col] = f2b(o[n8][r] / srow[r]);
    }
}

extern "C" void kernel_launch(void* const* d_in, const int* in_sizes, int n_in,
                              void* d_out, int out_size, void* d_ws, size_t ws_size,
                              hipStream_t stream) {
  const float* hidden = (const float*)d_in[0];
  const float* Wq = (const float*)d_in[1];
  const float* Wo = (const float*)d_in[2];
  const float* cache = (const float*)d_in[3];
  const int* btab = (const int*)d_in[4];
  float* out = (float*)d_out;
  char* ws = (char*)d_ws;

  ushort* WqT = (ushort*)(ws);                    // 33,554,432 B
  ushort* WoT = (ushort*)(ws + 33554432);         // 33,554,432 B
  ushort* Kb  = (ushort*)(ws + 67108864);         // 16,777,216 B
  ushort* Vb  = (ushort*)(ws + 83886080);         // 16,777,216 B
  ushort* Xb  = (ushort*)(ws + 100663296);        //  4,194,304 B
  float*  Qt  = (float*)(ws + 104857600);         //  8,388,608 B
  ushort* Qb  = (ushort*)(ws + 113246208);        //  4,194,304 B
  ushort* Cx  = (ushort*)(ws + 117440512);        //  4,194,304 B
  float*  ct  = (float*)(ws + 121634816);         //    131,072 B
  float*  st  = (float*)(ws + 121765888);         //    131,072 B

  cvt_hidden<<<dim3(2048), dim3(256), 0, stream>>>(hidden, Xb);
  transpose_cvt<<<dim3(128, 128), dim3(256), 0, stream>>>(Wq, WqT);
  transpose_cvt<<<dim3(128, 128), dim3(256), 0, stream>>>(Wo, WoT);
  gather_kv<<<dim3(16384), dim3(256), 0, stream>>>(cache, btab, Kb, Vb);
  rope_table<<<dim3(128), dim3(256), 0, stream>>>(ct, st);
  gemm_bt<<<dim3(8, 32), dim3(256), 0, stream>>>(Xb, WqT, Qt, 512, 4096, 4096);
  rope_apply<<<dim3(8192), dim3(256), 0, stream>>>(Qt, ct, st, Qb);
  attn<<<dim3(32, 8), dim3(256), 0, stream>>>(Qb, Kb, Vb, Cx);
  gemm_bt<<<dim3(8, 32), dim3(256), 0, stream>>>(Cx, WoT, out, 512, 4096, 4096);
}

// Round 4
// 576.898 us; speedup vs baseline: 2.0665x; 2.0665x over previous
//
#include <hip/hip_runtime.h>

typedef short bf16x8 __attribute__((ext_vector_type(8)));
typedef float f32x4 __attribute__((ext_vector_type(4)));

#define SEQ 512
#define HID 4096
#define TKV 8192
#define NS 2
#define TPS (TKV / NS)
#define KVB 64
#define NT (TPS / KVB)
#define SCALE 0.08838834764831845f  // 1/sqrt(128)

__device__ __forceinline__ ushort f2b(float f) {
  union { float f; unsigned u; } v; v.f = f;
  unsigned u = v.u;
  unsigned r = (u + 0x7FFFu + ((u >> 16) & 1u)) >> 16;  // RNE
  return (ushort)r;
}

// ---- async 16B global -> LDS (HW writes lds_base + lane*16) ----
#if __has_builtin(__builtin_amdgcn_global_load_lds)
typedef __attribute__((address_space(3))) unsigned int as3_uint;
typedef const __attribute__((address_space(1))) unsigned int as1_uint;
__device__ __forceinline__ void gll16(const void* g, void* l) {
  __builtin_amdgcn_global_load_lds((as1_uint*)g, (as3_uint*)l, 16, 0, 0);
}
#else
__device__ __forceinline__ void gll16(const void* g, void* l) {
  uint4 t = *(const uint4*)g;
  *(uint4*)((char*)l + (threadIdx.x & 63) * 16) = t;
}
#endif

// ---------- hidden fp32 -> bf16 ----------
__global__ __launch_bounds__(256) void cvt_hidden(const float* __restrict__ in, ushort* __restrict__ out) {
  int i = (blockIdx.x * 256 + threadIdx.x) * 4;
  float4 v = *(const float4*)(in + i);
  ushort4 o; o.x = f2b(v.x); o.y = f2b(v.y); o.z = f2b(v.z); o.w = f2b(v.w);
  *(ushort4*)(out + i) = o;
}

// ---------- W [K][N] fp32 -> WT [N][K] bf16 ----------
__global__ __launch_bounds__(256) void transpose_cvt(const float* __restrict__ W, ushort* __restrict__ WT) {
  __shared__ float tile[32][33];
  int bx = blockIdx.x, by = blockIdx.y;
  int x = threadIdx.x & 31, y0 = threadIdx.x >> 5;
#pragma unroll
  for (int yy = 0; yy < 32; yy += 8)
    tile[y0 + yy][x] = W[(by * 32 + y0 + yy) * HID + bx * 32 + x];
  __syncthreads();
#pragma unroll
  for (int yy = 0; yy < 32; yy += 8)
    WT[(bx * 32 + y0 + yy) * HID + by * 32 + x] = f2b(tile[x][y0 + yy]);
}

// ---------- K gather: cache[b][0][kvh][pos][d] fp32 -> Kb[kvh][t][d] bf16 ----------
__global__ __launch_bounds__(256) void gather_k(const float* __restrict__ cache, const int* __restrict__ btab,
                                                ushort* __restrict__ Kb) {
  int i = blockIdx.x * 256 + threadIdx.x;  // 2,097,152
  int d4  = i & 31;
  int pos = (i >> 5) & 15;
  int kvh = (i >> 9) & 7;
  int blk = i >> 12;
  int b = btab[blk];
  const float4 v = *(const float4*)(cache + (((long)(b * 2) * 8 + kvh) * 16 + pos) * 128 + d4 * 4);
  ushort4 o; o.x = f2b(v.x); o.y = f2b(v.y); o.z = f2b(v.z); o.w = f2b(v.w);
  *(ushort4*)(Kb + ((long)kvh * TKV + blk * 16 + pos) * 128 + d4 * 4) = o;
}

// ---------- V gather + transpose: cache[b][1][kvh][pos][d] fp32 -> Vt[kvh][d][t] bf16 ----------
__global__ __launch_bounds__(256) void gather_vt(const float* __restrict__ cache, const int* __restrict__ btab,
                                                 ushort* __restrict__ Vt) {
  __shared__ __align__(16) float tile[16][132];
  int bid = blockIdx.x;  // 4096 = 512 blk * 8 kvh
  int kvh = bid & 7, blk = bid >> 3;
  int b = btab[blk];
  const float* src = cache + (((long)(b * 2 + 1) * 8 + kvh) * 16) * 128;
  int tid = threadIdx.x;
#pragma unroll
  for (int p = 0; p < 2; p++) {
    int idx = tid + p * 256;
    int pos = idx >> 5, c4 = idx & 31;
    float4 v = *(const float4*)(src + pos * 128 + c4 * 4);
    *(float4*)&tile[pos][c4 * 4] = v;
  }
  __syncthreads();
  int d = tid >> 1, half = tid & 1;
  bf16x8 pk;
#pragma unroll
  for (int j = 0; j < 8; j++) pk[j] = (short)f2b(tile[half * 8 + j][d]);
  *(bf16x8*)(Vt + ((long)kvh * 128 + d) * TKV + blk * 16 + half * 8) = pk;
}

// ---------- RoPE tables (fp64 for accuracy) ----------
__global__ __launch_bounds__(256) void rope_table(float* __restrict__ ct, float* __restrict__ st) {
  int i = blockIdx.x * 256 + threadIdx.x;  // 512*64
  int s = i >> 6, j = i & 63;
  double invf = exp(-((double)(2 * j) / 128.0) * log(10000.0));
  double ang = (double)s * invf;
  ct[i] = (float)cos(ang);
  st[i] = (float)sin(ang);
}

// ---------- RoPE apply: Qt[s][h*128+d] fp32 -> Qb[h][s][d] bf16 ----------
__global__ __launch_bounds__(256) void rope_apply(const float* __restrict__ Qt, const float* __restrict__ ct,
                                                  const float* __restrict__ st, ushort* __restrict__ Qb) {
  int i = blockIdx.x * 256 + threadIdx.x;  // 2M
  int s = i >> 12;
  int hd = i & 4095;
  int h = hd >> 7, d = hd & 127;
  int j = d & 63;
  float c = ct[s * 64 + j], sn = st[s * 64 + j];
  float q = Qt[i];
  float qp = Qt[(d < 64) ? (i + 64) : (i - 64)];
  float rot = (d < 64) ? -qp : qp;
  Qb[((long)h * SEQ + s) * 128 + d] = f2b(q * c + rot * sn);
}

// ---------- GEMM: C[M][N] fp32 = A[M][K]bf16 * BT[N][K]^T ; BM=64 BN=128 BK=64 ----------
// global_load_lds + XOR-swizzled linear LDS + double buffer (m97 pattern).
__global__ __launch_bounds__(256, 1) void gemm2(const ushort* __restrict__ A, const ushort* __restrict__ BT,
                                                float* __restrict__ C, int M, int N, int K) {
  __shared__ __align__(16) ushort As[2][64 * 64];
  __shared__ __align__(16) ushort Bs[2][128 * 64];
  const int bm = blockIdx.x, bn = blockIdx.y;
  const int tid = threadIdx.x, lane = tid & 63, w = tid >> 6;
  const int wm = w >> 1, wn = w & 1;
  const int l15 = lane & 15, lg = lane >> 4;
  const int xr = l15 & 7;           // frag-read row xor
  const int sr = lane >> 3, sc = lane & 7;  // stage sub-row / chunk
  f32x4 acc[2][4] = {};

#define GSTAGE(B, KT) do {                                                            \
    _Pragma("unroll") for (int i_ = 0; i_ < 2; i_++) {                                \
      int r0 = (w * 2 + i_) * 8; int r = r0 + sr;                                     \
      gll16(A + (long)(bm * 64 + r) * K + (KT) + ((sc ^ (r & 7)) * 8), &As[B][r0 * 64]); } \
    _Pragma("unroll") for (int i_ = 0; i_ < 4; i_++) {                                \
      int r0 = (w * 4 + i_) * 8; int r = r0 + sr;                                     \
      gll16(BT + (long)(bn * 128 + r) * K + (KT) + ((sc ^ (r & 7)) * 8), &Bs[B][r0 * 64]); } \
  } while (0)

  GSTAGE(0, 0);
  __syncthreads();
  int buf = 0;
  for (int kt = 0; kt < K; kt += 64) {
    if (kt + 64 < K) GSTAGE(buf ^ 1, kt + 64);
#pragma unroll
    for (int kk = 0; kk < 2; kk++) {
      bf16x8 af[2], bfr[4];
#pragma unroll
      for (int m = 0; m < 2; m++) {
        int row = wm * 32 + m * 16 + l15;
        af[m] = *(const bf16x8*)(&As[buf][row * 64 + (((kk * 4 + lg) ^ xr) * 8)]);
      }
#pragma unroll
      for (int n = 0; n < 4; n++) {
        int row = wn * 64 + n * 16 + l15;
        bfr[n] = *(const bf16x8*)(&Bs[buf][row * 64 + (((kk * 4 + lg) ^ xr) * 8)]);
      }
#pragma unroll
      for (int m = 0; m < 2; m++)
#pragma unroll
        for (int n = 0; n < 4; n++)
          acc[m][n] = __builtin_amdgcn_mfma_f32_16x16x32_bf16(af[m], bfr[n], acc[m][n], 0, 0, 0);
    }
    __syncthreads();
    buf ^= 1;
  }
#pragma unroll
  for (int m = 0; m < 2; m++)
#pragma unroll
    for (int n = 0; n < 4; n++)
#pragma unroll
      for (int r = 0; r < 4; r++) {
        int row = bm * 64 + wm * 32 + m * 16 + lg * 4 + r;
        int col = bn * 128 + wn * 64 + n * 16 + l15;
        C[(long)row * N + col] = acc[m][n][r];
      }
#undef GSTAGE
}

// ---------- flash attention, KV-split NS=2, 8 waves (2 heads x 64 q-rows) ----------
// bid%8 = kvh  ->  each XCD streams one kvh's K/V (L2-resident).
__global__ __launch_bounds__(512, 1) void attn2(const ushort* __restrict__ Q, const ushort* __restrict__ Kc,
                                                const ushort* __restrict__ Vt, float* __restrict__ Op,
                                                float* __restrict__ ml) {
  __shared__ __align__(16) ushort Ks[2][64 * 128];
  __shared__ __align__(16) ushort Vs[2][128 * 64];
  __shared__ __align__(16) ushort Ps[8][16 * 72];
  const int bid = blockIdx.x;
  const int kvh = bid & 7;
  const int y = bid >> 3;        // 0..31
  const int ns = y >> 4;         // 0..1
  const int qb = (y >> 1) & 7;   // 0..7
  const int hpi = y & 1;         // 0..1
  const int tid = threadIdx.x, lane = tid & 63, w = tid >> 6;
  const int head = kvh * 4 + hpi * 2 + (w >> 2);
  const int wrow = (w & 3) * 16;
  const int l15 = lane & 15, lg = lane >> 4;
  const int xq = l15 & 7;
  const int kr = lane >> 4, kc = lane & 15;  // K stage: 4 rows/op, 16 chunks
  const int vr = lane >> 3, vc = lane & 7;   // V stage: 8 rows/op, 8 chunks
  const ushort* Kg = Kc + ((long)kvh * TKV + ns * TPS) * 128;
  const ushort* Vg = Vt + (long)kvh * 128 * TKV + ns * TPS;

  bf16x8 qf[4];
  {
    const ushort* qrow = Q + ((long)head * SEQ + qb * 64 + wrow + l15) * 128 + lg * 8;
#pragma unroll
    for (int kk = 0; kk < 4; kk++) qf[kk] = *(const bf16x8*)(qrow + kk * 32);
  }
  f32x4 o[8] = {};
  float mrow[4] = {-3e38f, -3e38f, -3e38f, -3e38f};
  float srow[4] = {0.f, 0.f, 0.f, 0.f};

#define STAGE(B, T0) do {                                                         \
    _Pragma("unroll") for (int i_ = 0; i_ < 2; i_++) {                            \
      int r0 = (w * 2 + i_) * 4; int r = r0 + kr;                                 \
      gll16(Kg + (long)((T0) + r) * 128 + ((kc ^ (r & 7)) * 8), &Ks[B][r0 * 128]); } \
    _Pragma("unroll") for (int i_ = 0; i_ < 2; i_++) {                            \
      int r0 = (w * 2 + i_) * 8; int r = r0 + vr;                                 \
      gll16(Vg + (long)r * TKV + (T0) + ((vc ^ (r & 7)) * 8), &Vs[B][r0 * 64]); } \
  } while (0)

  STAGE(0, 0);
  __syncthreads();
  int buf = 0;
  for (int t = 0; t < NT; t++) {
    if (t + 1 < NT) STAGE(buf ^ 1, (t + 1) * KVB);
    // QK^T
    f32x4 s[4] = {};
#pragma unroll
    for (int kk = 0; kk < 4; kk++)
#pragma unroll
      for (int n = 0; n < 4; n++) {
        int row = n * 16 + l15;
        bf16x8 kf = *(const bf16x8*)(&Ks[buf][row * 128 + (((kk * 4 + lg) ^ xq) * 8)]);
        s[n] = __builtin_amdgcn_mfma_f32_16x16x32_bf16(qf[kk], kf, s[n], 0, 0, 0);
      }
    // online softmax; row-sum kept lane-partial (reduced once at end)
    float pp[4][4];
#pragma unroll
    for (int r = 0; r < 4; r++) {
      float a = fmaxf(fmaxf(s[0][r], s[1][r]), fmaxf(s[2][r], s[3][r])) * SCALE;
#pragma unroll
      for (int m_ = 1; m_ < 16; m_ <<= 1) a = fmaxf(a, __shfl_xor(a, m_, 64));
      float mn = fmaxf(mrow[r], a);
      float al = __expf(mrow[r] - mn);
      mrow[r] = mn;
      float ls = 0.f;
#pragma unroll
      for (int n = 0; n < 4; n++) { float p = __expf(s[n][r] * SCALE - mn); pp[n][r] = p; ls += p; }
      srow[r] = srow[r] * al + ls;
#pragma unroll
      for (int n8 = 0; n8 < 8; n8++) o[n8][r] *= al;
    }
    // P -> LDS (wave-private, stride 72 = 16B-aligned rows)
#pragma unroll
    for (int n = 0; n < 4; n++)
#pragma unroll
      for (int r = 0; r < 4; r++)
        Ps[w][(lg * 4 + r) * 72 + n * 16 + l15] = f2b(pp[n][r]);
    // PV
#pragma unroll
    for (int kk = 0; kk < 2; kk++) {
      bf16x8 pf = *(const bf16x8*)(&Ps[w][l15 * 72 + kk * 32 + lg * 8]);
#pragma unroll
      for (int n8 = 0; n8 < 8; n8++) {
        int row = n8 * 16 + l15;
        bf16x8 vf = *(const bf16x8*)(&Vs[buf][row * 64 + (((kk * 4 + lg) ^ xq) * 8)]);
        o[n8] = __builtin_amdgcn_mfma_f32_16x16x32_bf16(pf, vf, o[n8], 0, 0, 0);
      }
    }
    __syncthreads();
    buf ^= 1;
  }
#undef STAGE
  // epilogue: unnormalized O + (m, l) per row
#pragma unroll
  for (int r = 0; r < 4; r++) {
    float rs = srow[r];
#pragma unroll
    for (int m_ = 1; m_ < 16; m_ <<= 1) rs += __shfl_xor(rs, m_, 64);
    int qg = qb * 64 + wrow + lg * 4 + r;
    float* ob = Op + ((long)(ns * 32 + head) * SEQ + qg) * 128;
#pragma unroll
    for (int n8 = 0; n8 < 8; n8++) ob[n8 * 16 + l15] = o[n8][r];
    if (l15 == 0) {
      float* mp = ml + ((long)(ns * 32 + head) * SEQ + qg) * 2;
      mp[0] = mrow[r];
      mp[1] = rs;
    }
  }
}

// ---------- merge NS=2 partials -> Cx[q][h*128+d] bf16 ----------
__global__ __launch_bounds__(256) void merge2(const float* __restrict__ Op, const float* __restrict__ ml,
                                              ushort* __restrict__ Cx) {
  int i = blockIdx.x * 256 + threadIdx.x;  // 524288
  int d4 = i & 31, h = (i >> 5) & 31, q = i >> 10;
  long b0 = (long)h * SEQ + q;
  long b1 = (long)(32 + h) * SEQ + q;
  float m0 = ml[b0 * 2], l0 = ml[b0 * 2 + 1];
  float m1 = ml[b1 * 2], l1 = ml[b1 * 2 + 1];
  float ma = fmaxf(m0, m1);
  float w0 = __expf(m0 - ma), w1 = __expf(m1 - ma);
  float inv = 1.f / (l0 * w0 + l1 * w1);
  float4 o0 = *(const float4*)(Op + b0 * 128 + d4 * 4);
  float4 o1 = *(const float4*)(Op + b1 * 128 + d4 * 4);
  ushort4 r;
  r.x = f2b((o0.x * w0 + o1.x * w1) * inv);
  r.y = f2b((o0.y * w0 + o1.y * w1) * inv);
  r.z = f2b((o0.z * w0 + o1.z * w1) * inv);
  r.w = f2b((o0.w * w0 + o1.w * w1) * inv);
  *(ushort4*)(Cx + (long)q * HID + h * 128 + d4 * 4) = r;
}

extern "C" void kernel_launch(void* const* d_in, const int* in_sizes, int n_in,
                              void* d_out, int out_size, void* d_ws, size_t ws_size,
                              hipStream_t stream) {
  const float* hidden = (const float*)d_in[0];
  const float* Wq = (const float*)d_in[1];
  const float* Wo = (const float*)d_in[2];
  const float* cache = (const float*)d_in[3];
  const int* btab = (const int*)d_in[4];
  float* out = (float*)d_out;
  char* ws = (char*)d_ws;

  ushort* WqT = (ushort*)(ws);                    // 33,554,432 B (reused by Op/ml during attn)
  float*  Op  = (float*)(ws);                     // 16,777,216 B (NS*32*512*128 fp32)
  float*  ml  = (float*)(ws + 16777216);          //    262,144 B
  ushort* WoT = (ushort*)(ws + 33554432);         // 33,554,432 B
  ushort* Kb  = (ushort*)(ws + 67108864);         // 16,777,216 B
  ushort* Vt  = (ushort*)(ws + 83886080);         // 16,777,216 B
  ushort* Xb  = (ushort*)(ws + 100663296);        //  4,194,304 B
  float*  Qt  = (float*)(ws + 104857600);         //  8,388,608 B
  ushort* Qb  = (ushort*)(ws + 113246208);        //  4,194,304 B
  ushort* Cx  = (ushort*)(ws + 117440512);        //  4,194,304 B
  float*  ct  = (float*)(ws + 121634816);         //    131,072 B
  float*  st  = (float*)(ws + 121765888);         //    131,072 B

  cvt_hidden<<<dim3(2048), dim3(256), 0, stream>>>(hidden, Xb);
  transpose_cvt<<<dim3(128, 128), dim3(256), 0, stream>>>(Wq, WqT);
  transpose_cvt<<<dim3(128, 128), dim3(256), 0, stream>>>(Wo, WoT);
  gather_k<<<dim3(8192), dim3(256), 0, stream>>>(cache, btab, Kb);
  gather_vt<<<dim3(4096), dim3(256), 0, stream>>>(cache, btab, Vt);
  rope_table<<<dim3(128), dim3(256), 0, stream>>>(ct, st);
  gemm2<<<dim3(8, 32), dim3(256), 0, stream>>>(Xb, WqT, Qt, 512, 4096, 4096);
  rope_apply<<<dim3(8192), dim3(256), 0, stream>>>(Qt, ct, st, Qb);
  attn2<<<dim3(256), dim3(512), 0, stream>>>(Qb, Kb, Vt, Op, ml);
  merge2<<<dim3(2048), dim3(256), 0, stream>>>(Op, ml, Cx);
  gemm2<<<dim3(8, 32), dim3(256), 0, stream>>>(Cx, WoT, out, 512, 4096, 4096);
}

// Round 9
// 520.844 us; speedup vs baseline: 2.2889x; 1.1076x over previous
//
#include <hip/hip_runtime.h>

typedef short bf16x8 __attribute__((ext_vector_type(8)));
typedef float f32x4 __attribute__((ext_vector_type(4)));

#define SEQ 512
#define HID 4096
#define TKV 8192
#define NS 2
#define TPS (TKV / NS)
#define KVB 64
#define NT (TPS / KVB)
#define SCALE 0.08838834764831845f  // 1/sqrt(128)

__device__ __forceinline__ ushort f2b(float f) {
  union { float f; unsigned u; } v; v.f = f;
  unsigned u = v.u;
  unsigned r = (u + 0x7FFFu + ((u >> 16) & 1u)) >> 16;  // RNE
  return (ushort)r;
}

// ---- async 16B global -> LDS (HW writes lds_base + lane*16) ----
#if __has_builtin(__builtin_amdgcn_global_load_lds)
typedef __attribute__((address_space(3))) unsigned int as3_uint;
typedef const __attribute__((address_space(1))) unsigned int as1_uint;
__device__ __forceinline__ void gll16(const void* g, void* l) {
  __builtin_amdgcn_global_load_lds((as1_uint*)g, (as3_uint*)l, 16, 0, 0);
}
#else
__device__ __forceinline__ void gll16(const void* g, void* l) {
  uint4 t = *(const uint4*)g;
  *(uint4*)((char*)l + (threadIdx.x & 63) * 16) = t;
}
#endif

// ---------- hidden fp32 -> bf16 ----------
__global__ __launch_bounds__(256) void cvt_hidden(const float* __restrict__ in, ushort* __restrict__ out) {
  int i = (blockIdx.x * 256 + threadIdx.x) * 4;
  float4 v = *(const float4*)(in + i);
  ushort4 o; o.x = f2b(v.x); o.y = f2b(v.y); o.z = f2b(v.z); o.w = f2b(v.w);
  *(ushort4*)(out + i) = o;
}

// ---------- W [K][N] fp32 -> WT [N][K] bf16 ; 64x64 tiles, 16B stores; z picks Wq/Wo ----------
__global__ __launch_bounds__(256) void transpose_cvt2(const float* __restrict__ Wq, ushort* __restrict__ WqT,
                                                      const float* __restrict__ Wo, ushort* __restrict__ WoT) {
  __shared__ __align__(16) float tile[64][68];
  const float* W = blockIdx.z ? Wo : Wq;
  ushort* WT = blockIdx.z ? WoT : WqT;
  int bx = blockIdx.x, by = blockIdx.y;
  int tid = threadIdx.x;
#pragma unroll
  for (int p = 0; p < 4; p++) {
    int idx = tid + p * 256;
    int r = idx >> 4, c4 = (idx & 15) * 4;
    *(float4*)&tile[r][c4] = *(const float4*)(W + (long)(by * 64 + r) * HID + bx * 64 + c4);
  }
  __syncthreads();
  int r = tid >> 2, q = tid & 3;
  bf16x8 a, b;
#pragma unroll
  for (int j = 0; j < 8; j++) {
    a[j] = (short)f2b(tile[q * 16 + j][r]);
    b[j] = (short)f2b(tile[q * 16 + 8 + j][r]);
  }
  long ob = (long)(bx * 64 + r) * HID + by * 64 + q * 16;
  *(bf16x8*)(WT + ob) = a;
  *(bf16x8*)(WT + ob + 8) = b;
}

// ---------- K gather: cache[b][0][kvh][pos][d] fp32 -> Kb[kvh][t][d] bf16 ----------
__global__ __launch_bounds__(256) void gather_k(const float* __restrict__ cache, const int* __restrict__ btab,
                                                ushort* __restrict__ Kb) {
  int i = blockIdx.x * 256 + threadIdx.x;  // 2,097,152
  int d4  = i & 31;
  int pos = (i >> 5) & 15;
  int kvh = (i >> 9) & 7;
  int blk = i >> 12;
  int b = btab[blk];
  const float4 v = *(const float4*)(cache + (((long)(b * 2) * 8 + kvh) * 16 + pos) * 128 + d4 * 4);
  ushort4 o; o.x = f2b(v.x); o.y = f2b(v.y); o.z = f2b(v.z); o.w = f2b(v.w);
  *(ushort4*)(Kb + ((long)kvh * TKV + blk * 16 + pos) * 128 + d4 * 4) = o;
}

// ---------- V gather + transpose: cache[b][1][kvh][pos][d] fp32 -> Vt[kvh][d][t] bf16 ----------
__global__ __launch_bounds__(256) void gather_vt(const float* __restrict__ cache, const int* __restrict__ btab,
                                                 ushort* __restrict__ Vt) {
  __shared__ __align__(16) float tile[16][132];
  int bid = blockIdx.x;  // 4096 = 512 blk * 8 kvh
  int kvh = bid & 7, blk = bid >> 3;
  int b = btab[blk];
  const float* src = cache + (((long)(b * 2 + 1) * 8 + kvh) * 16) * 128;
  int tid = threadIdx.x;
#pragma unroll
  for (int p = 0; p < 2; p++) {
    int idx = tid + p * 256;
    int pos = idx >> 5, c4 = idx & 31;
    float4 v = *(const float4*)(src + pos * 128 + c4 * 4);
    *(float4*)&tile[pos][c4 * 4] = v;
  }
  __syncthreads();
  int d = tid >> 1, half = tid & 1;
  bf16x8 pk;
#pragma unroll
  for (int j = 0; j < 8; j++) pk[j] = (short)f2b(tile[half * 8 + j][d]);
  *(bf16x8*)(Vt + ((long)kvh * 128 + d) * TKV + blk * 16 + half * 8) = pk;
}

// ---------- RoPE tables (fp64 for accuracy) ----------
__global__ __launch_bounds__(256) void rope_table(float* __restrict__ ct, float* __restrict__ st) {
  int i = blockIdx.x * 256 + threadIdx.x;  // 512*64
  int s = i >> 6, j = i & 63;
  double invf = exp(-((double)(2 * j) / 128.0) * log(10000.0));
  double ang = (double)s * invf;
  ct[i] = (float)cos(ang);
  st[i] = (float)sin(ang);
}

// ---------- RoPE apply (+fold 1/sqrt(D)): Qt[s][h*128+d] fp32 -> Qb[h][s][d] bf16 ----------
__global__ __launch_bounds__(256) void rope_apply(const float* __restrict__ Qt, const float* __restrict__ ct,
                                                  const float* __restrict__ st, ushort* __restrict__ Qb) {
  int i = blockIdx.x * 256 + threadIdx.x;  // 2M
  int s = i >> 12;
  int hd = i & 4095;
  int h = hd >> 7, d = hd & 127;
  int j = d & 63;
  float c = ct[s * 64 + j], sn = st[s * 64 + j];
  float q = Qt[i];
  float qp = Qt[(d < 64) ? (i + 64) : (i - 64)];
  float rot = (d < 64) ? -qp : qp;
  Qb[((long)h * SEQ + s) * 128 + d] = f2b((q * c + rot * sn) * SCALE);
}

// ---------- GEMM: C[M][N] fp32 = A[M][K]bf16 * BT[N][K]^T ; BM=64 BN=64 BK=64, 4 waves, 2 blk/CU ----------
__global__ __launch_bounds__(256, 2) void gemm3(const ushort* __restrict__ A, const ushort* __restrict__ BT,
                                                float* __restrict__ C, int M, int N, int K) {
  __shared__ __align__(16) ushort As[2][64 * 64];
  __shared__ __align__(16) ushort Bs[2][64 * 64];
  const int bm = blockIdx.x, bn = blockIdx.y;
  const int tid = threadIdx.x, lane = tid & 63, w = tid >> 6;
  const int wm = w >> 1, wn = w & 1;
  const int l15 = lane & 15, lg = lane >> 4;
  const int xr = l15 & 7;
  const int sr = lane >> 3, sc = lane & 7;
  f32x4 acc[2][2] = {};

#define GSTAGE(B, KT) do {                                                              \
    _Pragma("unroll") for (int i_ = 0; i_ < 2; i_++) {                                  \
      int r0 = (w * 2 + i_) * 8; int r = r0 + sr;                                       \
      gll16(A + (long)(bm * 64 + r) * K + (KT) + ((sc ^ (r & 7)) * 8), &As[B][r0 * 64]); } \
    _Pragma("unroll") for (int i_ = 0; i_ < 2; i_++) {                                  \
      int r0 = (w * 2 + i_) * 8; int r = r0 + sr;                                       \
      gll16(BT + (long)(bn * 64 + r) * K + (KT) + ((sc ^ (r & 7)) * 8), &Bs[B][r0 * 64]); } \
  } while (0)

  GSTAGE(0, 0);
  __syncthreads();
  int buf = 0;
  for (int kt = 0; kt < K; kt += 64) {
    if (kt + 64 < K) GSTAGE(buf ^ 1, kt + 64);
#pragma unroll
    for (int kk = 0; kk < 2; kk++) {
      bf16x8 af[2], bfr[2];
#pragma unroll
      for (int m = 0; m < 2; m++) {
        int row = wm * 32 + m * 16 + l15;
        af[m] = *(const bf16x8*)(&As[buf][row * 64 + (((kk * 4 + lg) ^ xr) * 8)]);
      }
#pragma unroll
      for (int n = 0; n < 2; n++) {
        int row = wn * 32 + n * 16 + l15;
        bfr[n] = *(const bf16x8*)(&Bs[buf][row * 64 + (((kk * 4 + lg) ^ xr) * 8)]);
      }
#pragma unroll
      for (int m = 0; m < 2; m++)
#pragma unroll
        for (int n = 0; n < 2; n++)
          acc[m][n] = __builtin_amdgcn_mfma_f32_16x16x32_bf16(af[m], bfr[n], acc[m][n], 0, 0, 0);
    }
    __syncthreads();
    buf ^= 1;
  }
#pragma unroll
  for (int m = 0; m < 2; m++)
#pragma unroll
    for (int n = 0; n < 2; n++)
#pragma unroll
      for (int r = 0; r < 4; r++) {
        int row = bm * 64 + wm * 32 + m * 16 + lg * 4 + r;
        int col = bn * 64 + wn * 32 + n * 16 + l15;
        C[(long)row * N + col] = acc[m][n][r];
      }
#undef GSTAGE
}

// ---------- flash attention: 4 waves = 1 head x 64 q-rows; KV-split NS=2; 2 blocks/CU ----------
// bid%8 = kvh -> each XCD streams one kvh's K/V (L2-resident).
__global__ __launch_bounds__(256, 2) void attn3(const ushort* __restrict__ Q, const ushort* __restrict__ Kc,
                                                const ushort* __restrict__ Vt, float* __restrict__ Op,
                                                float* __restrict__ ml) {
  __shared__ __align__(16) ushort Ks[2][64 * 128];
  __shared__ __align__(16) ushort Vs[2][128 * 64];
  __shared__ __align__(16) ushort Ps[4][16 * 72];
  const int bid = blockIdx.x;    // 512
  const int kvh = bid & 7;
  const int y = bid >> 3;        // 0..63
  const int ns = y >> 5;         // 0..1
  const int qb = (y >> 2) & 7;   // 0..7
  const int hpi = y & 3;         // 0..3
  const int head = kvh * 4 + hpi;
  const int tid = threadIdx.x, lane = tid & 63, w = tid >> 6;
  const int wrow = w * 16;
  const int l15 = lane & 15, lg = lane >> 4;
  const int xq = l15 & 7;
  const int kr = lane >> 4, kc = lane & 15;  // K stage: 4 rows/op, 16 chunks
  const int vr = lane >> 3, vc = lane & 7;   // V stage: 8 rows/op, 8 chunks
  const ushort* Kg = Kc + ((long)kvh * TKV + ns * TPS) * 128;
  const ushort* Vg = Vt + (long)kvh * 128 * TKV + ns * TPS;

  bf16x8 qf[4];
  {
    const ushort* qrow = Q + ((long)head * SEQ + qb * 64 + wrow + l15) * 128 + lg * 8;
#pragma unroll
    for (int kk = 0; kk < 4; kk++) qf[kk] = *(const bf16x8*)(qrow + kk * 32);
  }
  f32x4 o[8] = {};
  float mrow[4] = {-3e38f, -3e38f, -3e38f, -3e38f};
  float srow[4] = {0.f, 0.f, 0.f, 0.f};

#define STAGE(B, T0) do {                                                         \
    _Pragma("unroll") for (int i_ = 0; i_ < 4; i_++) {                            \
      int r0 = (w * 4 + i_) * 4; int r = r0 + kr;                                 \
      gll16(Kg + (long)((T0) + r) * 128 + ((kc ^ (r & 7)) * 8), &Ks[B][r0 * 128]); } \
    _Pragma("unroll") for (int i_ = 0; i_ < 4; i_++) {                            \
      int r0 = (w * 4 + i_) * 8; int r = r0 + vr;                                 \
      gll16(Vg + (long)r * TKV + (T0) + ((vc ^ (r & 7)) * 8), &Vs[B][r0 * 64]); } \
  } while (0)

  STAGE(0, 0);
  __syncthreads();
  int buf = 0;
  for (int t = 0; t < NT; t++) {
    if (t + 1 < NT) STAGE(buf ^ 1, (t + 1) * KVB);
    // QK^T (Q pre-scaled by 1/sqrt(D))
    f32x4 s[4] = {};
#pragma unroll
    for (int kk = 0; kk < 4; kk++)
#pragma unroll
      for (int n = 0; n < 4; n++) {
        int row = n * 16 + l15;
        bf16x8 kf = *(const bf16x8*)(&Ks[buf][row * 128 + (((kk * 4 + lg) ^ xq) * 8)]);
        s[n] = __builtin_amdgcn_mfma_f32_16x16x32_bf16(qf[kk], kf, s[n], 0, 0, 0);
      }
    // online softmax with defer-max (skip reduce+rescale when max growth <= 8)
    float m4[4];
#pragma unroll
    for (int r = 0; r < 4; r++)
      m4[r] = fmaxf(fmaxf(s[0][r], s[1][r]), fmaxf(s[2][r], s[3][r]));
    float dmax = fmaxf(fmaxf(m4[0] - mrow[0], m4[1] - mrow[1]),
                       fmaxf(m4[2] - mrow[2], m4[3] - mrow[3]));
    if (!__all(dmax <= 8.0f)) {
#pragma unroll
      for (int r = 0; r < 4; r++) {
        float a = m4[r];
#pragma unroll
        for (int m_ = 1; m_ < 16; m_ <<= 1) a = fmaxf(a, __shfl_xor(a, m_, 64));
        float mn = fmaxf(mrow[r], a);
        float al = __expf(mrow[r] - mn);
        mrow[r] = mn;
        srow[r] *= al;
#pragma unroll
        for (int n8 = 0; n8 < 8; n8++) o[n8][r] *= al;
      }
    }
    float pp[4][4];
#pragma unroll
    for (int r = 0; r < 4; r++) {
      float ls = 0.f;
#pragma unroll
      for (int n = 0; n < 4; n++) { float p = __expf(s[n][r] - mrow[r]); pp[n][r] = p; ls += p; }
      srow[r] += ls;
    }
    // P -> LDS (wave-private, stride 72 = 16B-aligned rows)
#pragma unroll
    for (int n = 0; n < 4; n++)
#pragma unroll
      for (int r = 0; r < 4; r++)
        Ps[w][(lg * 4 + r) * 72 + n * 16 + l15] = f2b(pp[n][r]);
    asm volatile("s_waitcnt lgkmcnt(0)" ::: "memory");
    // PV
#pragma unroll
    for (int kk = 0; kk < 2; kk++) {
      bf16x8 pf = *(const bf16x8*)(&Ps[w][l15 * 72 + kk * 32 + lg * 8]);
#pragma unroll
      for (int n8 = 0; n8 < 8; n8++) {
        int row = n8 * 16 + l15;
        bf16x8 vf = *(const bf16x8*)(&Vs[buf][row * 64 + (((kk * 4 + lg) ^ xq) * 8)]);
        o[n8] = __builtin_amdgcn_mfma_f32_16x16x32_bf16(pf, vf, o[n8], 0, 0, 0);
      }
    }
    __syncthreads();
    buf ^= 1;
  }
#undef STAGE
  // epilogue: unnormalized O + (m, l) per row
#pragma unroll
  for (int r = 0; r < 4; r++) {
    float rs = srow[r];
#pragma unroll
    for (int m_ = 1; m_ < 16; m_ <<= 1) rs += __shfl_xor(rs, m_, 64);
    int qg = qb * 64 + wrow + lg * 4 + r;
    float* ob = Op + ((long)(ns * 32 + head) * SEQ + qg) * 128;
#pragma unroll
    for (int n8 = 0; n8 < 8; n8++) ob[n8 * 16 + l15] = o[n8][r];
    if (l15 == 0) {
      float* mp = ml + ((long)(ns * 32 + head) * SEQ + qg) * 2;
      mp[0] = mrow[r];
      mp[1] = rs;
    }
  }
}

// ---------- merge NS=2 partials -> Cx[q][h*128+d] bf16 ----------
__global__ __launch_bounds__(256) void merge2(const float* __restrict__ Op, const float* __restrict__ ml,
                                              ushort* __restrict__ Cx) {
  int i = blockIdx.x * 256 + threadIdx.x;  // 524288
  int d4 = i & 31, h = (i >> 5) & 31, q = i >> 10;
  long b0 = (long)h * SEQ + q;
  long b1 = (long)(32 + h) * SEQ + q;
  float m0 = ml[b0 * 2], l0 = ml[b0 * 2 + 1];
  float m1 = ml[b1 * 2], l1 = ml[b1 * 2 + 1];
  float ma = fmaxf(m0, m1);
  float w0 = __expf(m0 - ma), w1 = __expf(m1 - ma);
  float inv = 1.f / (l0 * w0 + l1 * w1);
  float4 o0 = *(const float4*)(Op + b0 * 128 + d4 * 4);
  float4 o1 = *(const float4*)(Op + b1 * 128 + d4 * 4);
  ushort4 r;
  r.x = f2b((o0.x * w0 + o1.x * w1) * inv);
  r.y = f2b((o0.y * w0 + o1.y * w1) * inv);
  r.z = f2b((o0.z * w0 + o1.z * w1) * inv);
  r.w = f2b((o0.w * w0 + o1.w * w1) * inv);
  *(ushort4*)(Cx + (long)q * HID + h * 128 + d4 * 4) = r;
}

extern "C" void kernel_launch(void* const* d_in, const int* in_sizes, int n_in,
                              void* d_out, int out_size, void* d_ws, size_t ws_size,
                              hipStream_t stream) {
  const float* hidden = (const float*)d_in[0];
  const float* Wq = (const float*)d_in[1];
  const float* Wo = (const float*)d_in[2];
  const float* cache = (const float*)d_in[3];
  const int* btab = (const int*)d_in[4];
  float* out = (float*)d_out;
  char* ws = (char*)d_ws;

  ushort* WqT = (ushort*)(ws);                    // 33,554,432 B (reused by Op/ml during attn)
  float*  Op  = (float*)(ws);                     // 16,777,216 B (NS*32*512*128 fp32)
  float*  ml  = (float*)(ws + 16777216);          //    262,144 B
  ushort* WoT = (ushort*)(ws + 33554432);         // 33,554,432 B
  ushort* Kb  = (ushort*)(ws + 67108864);         // 16,777,216 B
  ushort* Vt  = (ushort*)(ws + 83886080);         // 16,777,216 B
  ushort* Xb  = (ushort*)(ws + 100663296);        //  4,194,304 B
  float*  Qt  = (float*)(ws + 104857600);         //  8,388,608 B
  ushort* Qb  = (ushort*)(ws + 113246208);        //  4,194,304 B
  ushort* Cx  = (ushort*)(ws + 117440512);        //  4,194,304 B
  float*  ct  = (float*)(ws + 121634816);         //    131,072 B
  float*  st  = (float*)(ws + 121765888);         //    131,072 B

  cvt_hidden<<<dim3(2048), dim3(256), 0, stream>>>(hidden, Xb);
  transpose_cvt2<<<dim3(64, 64, 2), dim3(256), 0, stream>>>(Wq, WqT, Wo, WoT);
  gather_k<<<dim3(8192), dim3(256), 0, stream>>>(cache, btab, Kb);
  gather_vt<<<dim3(4096), dim3(256), 0, stream>>>(cache, btab, Vt);
  rope_table<<<dim3(128), dim3(256), 0, stream>>>(ct, st);
  gemm3<<<dim3(8, 64), dim3(256), 0, stream>>>(Xb, WqT, Qt, 512, 4096, 4096);
  rope_apply<<<dim3(8192), dim3(256), 0, stream>>>(Qt, ct, st, Qb);
  attn3<<<dim3(512), dim3(256), 0, stream>>>(Qb, Kb, Vt, Op, ml);
  merge2<<<dim3(2048), dim3(256), 0, stream>>>(Op, ml, Cx);
  gemm3<<<dim3(8, 64), dim3(256), 0, stream>>>(Cx, WoT, out, 512, 4096, 4096);
}